// Round 16
// baseline (84.181 us; speedup 1.0000x reference)
//
#include <hip/hip_runtime.h>
#include <hip/hip_bf16.h>

typedef __attribute__((ext_vector_type(8))) short bf16x8;
typedef __attribute__((ext_vector_type(4))) float f32x4;

#define HW_   252
#define PLANE 63504            // 252*252
#define NCH   32
#define WS_NEED (25600u * 2u)  // packed weights only

__device__ __forceinline__ unsigned short f2bf(float f) {
    unsigned u = __builtin_bit_cast(unsigned, f);
    u += 0x7FFFu + ((u >> 16) & 1u);   // round-to-nearest-even
    return (unsigned short)(u >> 16);
}

// padded coord p -> source index: circular mod 256, then reflect(p-2)
__device__ __forceinline__ int padmap(int p) {
    int t = (p & 255) - 2;
    t = t < 0 ? -t : t;
    return t > 251 ? 502 - t : t;
}

// wp[t][o][ci] = bf16(w[o][ci][4-da][4-db]), t = da*5+db
__global__ void pack_w_kernel(const float* __restrict__ w, unsigned short* __restrict__ wp) {
    int e = blockIdx.x * 256 + threadIdx.x;   // [25][32][32]
    if (e >= 25600) return;
    int ci = e & 31;
    int o  = (e >> 5) & 31;
    int t  = e >> 10;
    int da = t / 5, db = t - da * 5;
    wp[e] = f2bf(w[((o * 32 + ci) * 5 + (4 - da)) * 5 + (4 - db)]);
}

// Fused conv v9: staging via width-4 global_load_lds DMA (per-lane source
// address -> pad folded in, NO pre-pass) + LDS fp32->bf16 convert phase.
// 4 chunks x 8 rows, ping-pong fp32 buffers; DMA(c+1) overlaps convert(c).
// MFMA loop + swapped-operand float4 store = v8 verbatim.
__global__ __launch_bounds__(256, 2) void conv_fused_v9(
    const float* __restrict__ x,
    const unsigned short* __restrict__ wp,
    float* __restrict__ out)
{
    __shared__ unsigned short xl[32 * 20 * 32];   // 40960 B bf16 patch [pr][col][g][ci8]
    __shared__ float fbA[8 * 20 * 32];            // 20480 B fp32 chunk [rl][col][ci]
    __shared__ float fbB[8 * 20 * 32];            // 20480 B

    const int tid  = threadIdx.x;
    const int orig = blockIdx.x;                  // 1152 blocks = 8 XCD * 144
    const int b    = orig & 7;                    // XCD-bijective: image b per XCD
    const int idx  = orig >> 3;                   // 0..143
    const int rt   = idx >> 4;                    // 0..8
    const int ct   = idx & 15;                    // 0..15
    const int i0 = rt * 28, j0 = ct * 16;

    const int wv   = tid >> 6;                    // wave id 0..3
    const int half = (tid >> 5) & 1;              // lane<32 ? 0 : 1
    const bool interior = (j0 != 0) && (j0 != 240);

    // per-lane plane base: ci = lane&31 = tid&31
    const float* pb = x + (size_t)b * NCH * PLANE + (size_t)(tid & 31) * PLANE;

    // ---- DMA one 8-row chunk into fb: 20 width-4 gld_lds per wave ----
    // instr i: row = c*8 + wv*2 + (i>=10); lanes<32 -> col 2i%20, >=32 -> +1
    // fbuf layout [rl][col][ci]: unit u = (rl*20+col)*32+ci; wave wv owns
    // units [wv*1280, wv*1280+1280) -> dest = fb + wv*1280 + i*64 (+lane*4 by HW)
    auto DMA = [&](int c, float* fb) {
        const int rb = i0 + 1 + c * 8 + wv * 2;
        const int mrLo = padmap(rb);
        const int mrHi = padmap(rb + 1);
        #pragma unroll
        for (int i = 0; i < 20; ++i) {
            const int mr = (i >= 10) ? mrHi : mrLo;
            const int ca = (2 * i) % 20;
            int mcA, mcB;
            if (interior) { mcA = j0 - 1 + ca; mcB = j0 + ca; }
            else { mcA = padmap(j0 + 1 + ca); mcB = padmap(j0 + 2 + ca); }
            const int mc = half ? mcB : mcA;
            const float* src = pb + (size_t)mr * HW_ + mc;
            __builtin_amdgcn_global_load_lds(
                (const __attribute__((address_space(1))) void*)src,
                (__attribute__((address_space(3))) void*)(fb + wv * 1280 + i * 64),
                4, 0, 0);
        }
    };

    // ---- convert one chunk: 640 tasks (rl,col,g); linear read (32B) &
    // linear write (16B) -> conflict-free both sides ----
    auto CONVERT = [&](int c, const float* fb) {
        #pragma unroll
        for (int it = 0; it < 3; ++it) {
            int t = it * 256 + tid;
            if (t < 640) {
                int g  = t & 3;
                int cc = t >> 2;                  // rl*20+col, 0..159
                const char* rbp = reinterpret_cast<const char*>(fb) + cc * 128 + g * 32;
                float4 f0 = *reinterpret_cast<const float4*>(rbp);
                float4 f1 = *reinterpret_cast<const float4*>(rbp + 16);
                unsigned short pk[8] = {
                    f2bf(f0.x), f2bf(f0.y), f2bf(f0.z), f2bf(f0.w),
                    f2bf(f1.x), f2bf(f1.y), f2bf(f1.z), f2bf(f1.w)};
                *reinterpret_cast<uint4*>(reinterpret_cast<char*>(xl)
                    + ((size_t)(c * 160 + cc) * 4 + g) * 16)
                    = *reinterpret_cast<const uint4*>(pk);
            }
        }
    };

    DMA(0, fbA);
    __syncthreads();                 // drains vmcnt(0): chunk 0 landed
    #pragma unroll
    for (int c = 0; c < 4; ++c) {
        if (c < 3) DMA(c + 1, (c & 1) ? fbA : fbB);   // overlap with convert(c)
        CONVERT(c, (c & 1) ? fbB : fbA);
        __syncthreads();             // convert done + next chunk landed
    }

    // ---- MFMA phase: v8 verbatim (swapped operands, float4 stores) ----
    const int lane = tid & 63;
    const int lm   = lane & 15;    // X pixel col (A row m) / o (B col n)
    const int lg   = lane >> 4;    // k-group; D row = lg*4+q = j-within-tile
    const int rowb = wv * 7;       // wave's first local output row

    const char* xlb = reinterpret_cast<const char*>(xl);
    const char* wb  = reinterpret_cast<const char*>(wp);
    const int afix  = (lm << 6) + (lg << 4);

    f32x4 acc[7][2];
    #pragma unroll
    for (int r = 0; r < 7; ++r) {
        acc[r][0] = (f32x4){0.f, 0.f, 0.f, 0.f};
        acc[r][1] = (f32x4){0.f, 0.f, 0.f, 0.f};
    }

    #pragma unroll
    for (int db = 0; db < 5; ++db) {
        bf16x8 a[5][2];
        #pragma unroll
        for (int da = 0; da < 5; ++da) {
            const char* ap = wb + ((da * 5 + db) << 11) + afix;
            a[da][0] = *reinterpret_cast<const bf16x8*>(ap);
            a[da][1] = *reinterpret_cast<const bf16x8*>(ap + 1024);
        }

        #pragma unroll
        for (int l = 0; l < 11; ++l) {
            bf16x8 bf = *reinterpret_cast<const bf16x8*>(
                xlb + (rowb + l) * 1280 + ((lm + db) << 6) + (lg << 4));
            #pragma unroll
            for (int da = 0; da < 5; ++da) {
                const int r = l - da;
                if (r >= 0 && r < 7) {
                    acc[r][0] = __builtin_amdgcn_mfma_f32_16x16x32_bf16(
                        bf, a[da][0], acc[r][0], 0, 0, 0);
                    acc[r][1] = __builtin_amdgcn_mfma_f32_16x16x32_bf16(
                        bf, a[da][1], acc[r][1], 0, 0, 0);
                }
            }
        }
    }

    // store: lane holds 4 consecutive j (q) for o = mt*16+lm -> ONE float4.
    const int jq = j0 + (lg << 2);
    if (jq + 3 < HW_) {
        #pragma unroll
        for (int r = 0; r < 7; ++r) {
            const int i = i0 + rowb + r;
            #pragma unroll
            for (int mt = 0; mt < 2; ++mt) {
                float* dst = out + ((size_t)(b * NCH + mt * 16 + lm)) * PLANE
                           + (size_t)i * HW_ + jq;
                *reinterpret_cast<float4*>(dst) =
                    *reinterpret_cast<const float4*>(&acc[r][mt]);
            }
        }
    }
}

// ---------------- fallback (ws too small): R2-style single kernel ----------------
__global__ __launch_bounds__(256) void conv_mfma_fb(
    const float* __restrict__ x,
    const float* __restrict__ w_raw,
    float* __restrict__ out)
{
    __shared__ unsigned short xl[12800];
    __shared__ unsigned short wl[25600];
    __shared__ int rmap[20], cmap[20];

    const int tid = threadIdx.x;
    const int bid = blockIdx.x;
    const int b  = bid >> 8;
    const int rt = (bid >> 4) & 15;
    const int ct = bid & 15;
    const int i0 = rt * 16, j0 = ct * 16;

    if (tid < 40) {
        int k    = tid < 20 ? tid : tid - 20;
        int base = tid < 20 ? i0  : j0;
        int r = (base + 1 + k) & 255;
        int t = r - 2;
        int m = t < 0 ? -t : (t > 251 ? 502 - t : t);
        if (tid < 20) rmap[k] = m; else cmap[k] = m;
    }
    for (int e = tid; e < 25600; e += 256) {
        int o   = e / 800;
        int rem = e - o * 800;
        int ci  = rem / 25;
        int kd  = rem - ci * 25;
        wl[(24 - kd) * 1024 + o * 32 + ci] = f2bf(w_raw[e]);
    }
    __syncthreads();

    for (int task = tid; task < 1600; task += 256) {
        int col = task % 20;
        int g   = (task / 20) & 3;
        int row = task / 80;
        const float* src = x + (size_t)(b * NCH + g * 8) * PLANE
                             + (size_t)rmap[row] * HW_ + cmap[col];
        unsigned short pk[8];
        #pragma unroll
        for (int q = 0; q < 8; ++q) pk[q] = f2bf(src[q * PLANE]);
        int off = ((row * 20 + col) << 6) + ((g ^ (col & 3)) << 4);
        *reinterpret_cast<uint4*>(reinterpret_cast<char*>(xl) + off)
            = *reinterpret_cast<const uint4*>(pk);
    }
    __syncthreads();

    const int lane  = tid & 63;
    const int wid   = tid >> 6;
    const int lm    = lane & 15;
    const int lg    = lane >> 4;
    const int rbase = wid * 4;

    f32x4 acc[4][2];
    #pragma unroll
    for (int rr = 0; rr < 4; ++rr) {
        acc[rr][0] = (f32x4){0.f, 0.f, 0.f, 0.f};
        acc[rr][1] = (f32x4){0.f, 0.f, 0.f, 0.f};
    }

    const char* wbase = (const char*)wl;
    const int afix = (lm << 6) + (lg << 4);
    const char* xlb = reinterpret_cast<const char*>(xl);

    #pragma unroll
    for (int da = 0; da < 5; ++da) {
        #pragma unroll
        for (int db = 0; db < 5; ++db) {
            const int t = da * 5 + db;
            bf16x8 a0 = *reinterpret_cast<const bf16x8*>(wbase + (t << 11) + afix);
            bf16x8 a1 = *reinterpret_cast<const bf16x8*>(wbase + (t << 11) + 1024 + afix);
            const int col  = lm + db;
            const int coff = (col << 6) + ((lg ^ (col & 3)) << 4);
            #pragma unroll
            for (int rr = 0; rr < 4; ++rr) {
                const int row = rbase + rr + da;
                bf16x8 bf = *reinterpret_cast<const bf16x8*>(xlb + row * 1280 + coff);
                acc[rr][0] = __builtin_amdgcn_mfma_f32_16x16x32_bf16(a0, bf, acc[rr][0], 0, 0, 0);
                acc[rr][1] = __builtin_amdgcn_mfma_f32_16x16x32_bf16(a1, bf, acc[rr][1], 0, 0, 0);
            }
        }
    }

    const int j = j0 + lm;
    #pragma unroll
    for (int rr = 0; rr < 4; ++rr) {
        const int i = i0 + rbase + rr;
        if (i < HW_ && j < HW_) {
            size_t rowoff = (size_t)(b * NCH) * PLANE + (size_t)i * HW_ + j;
            #pragma unroll
            for (int mt = 0; mt < 2; ++mt)
                #pragma unroll
                for (int q = 0; q < 4; ++q) {
                    int o = mt * 16 + lg * 4 + q;
                    out[rowoff + (size_t)o * PLANE] = acc[rr][mt][q];
                }
        }
    }
}

extern "C" void kernel_launch(void* const* d_in, const int* in_sizes, int n_in,
                              void* d_out, int out_size, void* d_ws, size_t ws_size,
                              hipStream_t stream) {
    const float* x = (const float*)d_in[0];
    const float* w = (const float*)d_in[1];
    float* out = (float*)d_out;

    if (ws_size >= WS_NEED) {
        unsigned short* wp = (unsigned short*)d_ws;
        hipLaunchKernelGGL(pack_w_kernel, dim3(100), dim3(256), 0, stream, w, wp);
        hipLaunchKernelGGL(conv_fused_v9, dim3(1152), dim3(256), 0, stream,
                           x, (const unsigned short*)wp, out);
    } else {
        hipLaunchKernelGGL(conv_mfma_fb, dim3(2048), dim3(256), 0, stream, x, w, out);
    }
}